// Round 1
// baseline (287.103 us; speedup 1.0000x reference)
//
#include <hip/hip_runtime.h>
#include <hip/hip_bf16.h>
#include <math.h>

// Problem constants
#define NB    4
#define NPTS  1024
#define DD    256
#define HH    64
#define WW    64
#define HWW   4096
#define NHEAD 8
#define DHD   32

typedef short s8v  __attribute__((ext_vector_type(8)));   // 8 x bf16 bits
typedef float f4v  __attribute__((ext_vector_type(4)));

#define MFMA_BF16 __builtin_amdgcn_mfma_f32_16x16x32_bf16

// -log(10000)/256
#define PE_FACT (-9.210340371976184f / 256.0f)

// ---------------------------------------------------------------------------
// K1: lf_pe = local_feat + pos_enc(32x32 grid); store fp32 (residual) + bf16
// ---------------------------------------------------------------------------
__global__ __launch_bounds__(256) void prep_local(const float* __restrict__ lf,
                                                  float* __restrict__ lf_pe_f32,
                                                  __hip_bfloat16* __restrict__ lf_pe_b) {
    int idx = blockIdx.x * 256 + threadIdx.x;      // < 4*1024*256
    int c = idx & 255;
    int p = (idx >> 8) & 1023;
    float div = __expf((float)(c & ~1) * PE_FACT);
    float pe;
    if (c & 1) {
        float y = (float)(p >> 5) * (1.0f / 31.0f);
        pe = __cosf(y * div);
    } else {
        float x = (float)(p & 31) * (1.0f / 31.0f);
        pe = __sinf(x * div);
    }
    float v = lf[idx] + pe;
    lf_pe_f32[idx] = v;
    lf_pe_b[idx] = __float2bfloat16(v);
}

// ---------------------------------------------------------------------------
// K2: gf_pe[n,p,c] = global_feat[n,c,p] + pos_enc(64x64 grid)  (LDS transpose)
// ---------------------------------------------------------------------------
__global__ __launch_bounds__(1024) void prep_global(const float* __restrict__ gfeat,
                                                    __hip_bfloat16* __restrict__ gf_pe_b) {
    __shared__ float tile[32][33];
    int n  = blockIdx.z;
    int p0 = blockIdx.x * 32;
    int c0 = blockIdx.y * 32;
    int tx = threadIdx.x, ty = threadIdx.y;
    tile[ty][tx] = gfeat[((size_t)n * DD + (c0 + ty)) * HWW + p0 + tx];
    __syncthreads();
    int p = p0 + ty, c = c0 + tx;
    float div = __expf((float)(c & ~1) * PE_FACT);
    float pe;
    if (c & 1) {
        float y = (float)(p >> 6) * (1.0f / 63.0f);
        pe = __cosf(y * div);
    } else {
        float x = (float)(p & 63) * (1.0f / 63.0f);
        pe = __sinf(x * div);
    }
    gf_pe_b[((size_t)n * HWW + p) * DD + c] = __float2bfloat16(tile[tx][ty] + pe);
}

// ---------------------------------------------------------------------------
// K3: weights -> bf16 (Wq | Wk | Wv | Wo packed consecutively)
// ---------------------------------------------------------------------------
__global__ __launch_bounds__(256) void w2b(const float* __restrict__ wq, const float* __restrict__ wk,
                                           const float* __restrict__ wv, const float* __restrict__ wo,
                                           __hip_bfloat16* __restrict__ out) {
    int idx = blockIdx.x * 256 + threadIdx.x;      // < 4*65536
    int m = idx >> 16, r = idx & 65535;
    const float* src = (m == 0) ? wq : (m == 1) ? wk : (m == 2) ? wv : wo;
    out[idx] = __float2bfloat16(src[r]);
}

// ---------------------------------------------------------------------------
// K4: GEMM  out = A(M,256) @ W^T(256,256) + bias
//   block = 256 thr (4 waves); block tile 64 rows x 64 cols; wave = 16x64.
//   MODE 0: Q  -> bf16 (n,h,NP,32)
//   MODE 1: K  -> bf16 (n,h,HW,32)
//   MODE 2: V  -> bf16 transposed (n,h,32,HW)
//   MODE 3: fp32 (M,256) to d_out
// ---------------------------------------------------------------------------
template <int MODE>
__global__ __launch_bounds__(256) void gemm256(const __hip_bfloat16* __restrict__ A,
                                               const __hip_bfloat16* __restrict__ Wb,
                                               const float* __restrict__ bias,
                                               void* __restrict__ outp) {
    int wave = threadIdx.x >> 6;
    int lane = threadIdx.x & 63;
    int quad = lane >> 4, c16 = lane & 15;
    int m0 = blockIdx.x * 64 + wave * 16;
    int c0 = blockIdx.y * 64;
    const short* Ab = (const short*)A;
    const short* Wp = (const short*)Wb;

    f4v acc0 = {0.f, 0.f, 0.f, 0.f}, acc1 = acc0, acc2 = acc0, acc3 = acc0;
    int arow = (m0 + c16) * DD + quad * 8;
#pragma unroll
    for (int ks = 0; ks < 8; ++ks) {
        s8v a  = *(const s8v*)(Ab + arow + ks * 32);
        s8v b0 = *(const s8v*)(Wp + (c0 +  0 + c16) * DD + ks * 32 + quad * 8);
        s8v b1 = *(const s8v*)(Wp + (c0 + 16 + c16) * DD + ks * 32 + quad * 8);
        s8v b2 = *(const s8v*)(Wp + (c0 + 32 + c16) * DD + ks * 32 + quad * 8);
        s8v b3 = *(const s8v*)(Wp + (c0 + 48 + c16) * DD + ks * 32 + quad * 8);
        acc0 = MFMA_BF16(a, b0, acc0, 0, 0, 0);
        acc1 = MFMA_BF16(a, b1, acc1, 0, 0, 0);
        acc2 = MFMA_BF16(a, b2, acc2, 0, 0, 0);
        acc3 = MFMA_BF16(a, b3, acc3, 0, 0, 0);
    }
#pragma unroll
    for (int t = 0; t < 4; ++t) {
        f4v acc = (t == 0) ? acc0 : (t == 1) ? acc1 : (t == 2) ? acc2 : acc3;
        int col = c0 + t * 16 + c16;
        float bv = bias[col];
#pragma unroll
        for (int r = 0; r < 4; ++r) {
            int row = m0 + quad * 4 + r;
            float v = acc[r] + bv;
            if (MODE == 0) {            // Q: (n,h,NP,32)
                int n = row >> 10, p = row & 1023, h = col >> 5, dh = col & 31;
                ((__hip_bfloat16*)outp)[(((size_t)(n * NHEAD + h) << 10) + p) * DHD + dh] = __float2bfloat16(v);
            } else if (MODE == 1) {     // K: (n,h,HW,32)
                int n = row >> 12, p = row & 4095, h = col >> 5, dh = col & 31;
                ((__hip_bfloat16*)outp)[(((size_t)(n * NHEAD + h) << 12) + p) * DHD + dh] = __float2bfloat16(v);
            } else if (MODE == 2) {     // Vt: (n,h,32,HW)
                int n = row >> 12, p = row & 4095, h = col >> 5, dh = col & 31;
                ((__hip_bfloat16*)outp)[(((size_t)(n * NHEAD + h) * DHD + dh) << 12) + p] = __float2bfloat16(v);
            } else {                    // fp32 out
                ((float*)outp)[(size_t)row * DD + col] = v;
            }
        }
    }
}

// ---------------------------------------------------------------------------
// K5: flash attention.  grid (NP/64, N*HEADS), block 256 (4 waves).
//   wave handles 16 q-rows, sweeps all 4096 keys in 32-key steps.
//   out = softmax(Q K^T / sqrt(32)) V + lf_pe   -> bf16 (n, p, 256)
// ---------------------------------------------------------------------------
__global__ __launch_bounds__(256) void attn(const __hip_bfloat16* __restrict__ Q,
                                            const __hip_bfloat16* __restrict__ K,
                                            const __hip_bfloat16* __restrict__ Vt,
                                            const float* __restrict__ lf_pe,
                                            __hip_bfloat16* __restrict__ outb) {
    __shared__ __align__(16) __hip_bfloat16 plds[4][16][32];
    int wave = threadIdx.x >> 6, lane = threadIdx.x & 63;
    int quad = lane >> 4, c16 = lane & 15;
    int bh = blockIdx.y;                 // n*8 + h
    int m0 = blockIdx.x * 64 + wave * 16;

    const short* Qs = (const short*)Q + (size_t)bh * NPTS * DHD;
    const short* Ks = (const short*)K + (size_t)bh * HWW * DHD;
    const short* Vs = (const short*)Vt + (size_t)bh * DHD * HWW;

    s8v aq = *(const s8v*)(Qs + (m0 + c16) * DHD + quad * 8);

    f4v o0 = {0.f, 0.f, 0.f, 0.f}, o1 = {0.f, 0.f, 0.f, 0.f};
    const f4v zf = {0.f, 0.f, 0.f, 0.f};
    float mrow[4] = {-INFINITY, -INFINITY, -INFINITY, -INFINITY};
    float lrow[4] = {0.f, 0.f, 0.f, 0.f};

    for (int j0 = 0; j0 < HWW; j0 += 32) {
        s8v kb0 = *(const s8v*)(Ks + (j0 +  0 + c16) * DHD + quad * 8);
        s8v kb1 = *(const s8v*)(Ks + (j0 + 16 + c16) * DHD + quad * 8);
        f4v s0 = MFMA_BF16(aq, kb0, zf, 0, 0, 0);   // rows quad*4+r, cols j0+c16
        f4v s1 = MFMA_BF16(aq, kb1, zf, 0, 0, 0);   // cols j0+16+c16

#pragma unroll
        for (int r = 0; r < 4; ++r) {
            float a = s0[r] * 0.17677669529663687f;   // 1/sqrt(32)
            float b = s1[r] * 0.17677669529663687f;
            float mx = fmaxf(a, b);
            mx = fmaxf(mx, __shfl_xor(mx, 1, 16));
            mx = fmaxf(mx, __shfl_xor(mx, 2, 16));
            mx = fmaxf(mx, __shfl_xor(mx, 4, 16));
            mx = fmaxf(mx, __shfl_xor(mx, 8, 16));
            float nm = fmaxf(mrow[r], mx);
            float alpha = __expf(mrow[r] - nm);
            float p0 = __expf(a - nm);
            float p1 = __expf(b - nm);
            float ts = p0 + p1;
            ts += __shfl_xor(ts, 1, 16);
            ts += __shfl_xor(ts, 2, 16);
            ts += __shfl_xor(ts, 4, 16);
            ts += __shfl_xor(ts, 8, 16);
            lrow[r] = lrow[r] * alpha + ts;
            mrow[r] = nm;
            o0[r] *= alpha;
            o1[r] *= alpha;
            // P (C-layout) -> LDS  [row][key]
            plds[wave][quad * 4 + r][c16]      = __float2bfloat16(p0);
            plds[wave][quad * 4 + r][16 + c16] = __float2bfloat16(p1);
        }
        // read back as A-operand layout: row = c16, k = quad*8+j (contiguous)
        s8v pa = *(const s8v*)(&plds[wave][c16][quad * 8]);
        s8v v0 = *(const s8v*)(Vs + (size_t)( 0 + c16) * HWW + j0 + quad * 8);
        s8v v1 = *(const s8v*)(Vs + (size_t)(16 + c16) * HWW + j0 + quad * 8);
        o0 = MFMA_BF16(pa, v0, o0, 0, 0, 0);   // rows quad*4+r, cols dh=c16
        o1 = MFMA_BF16(pa, v1, o1, 0, 0, 0);   // cols dh=16+c16
    }

    int b = bh >> 3, h = bh & 7;
#pragma unroll
    for (int r = 0; r < 4; ++r) {
        float inv = 1.0f / lrow[r];
        int q = m0 + quad * 4 + r;
        size_t base = (((size_t)b << 10) + q) * DD + (h << 5);
        float v0f = o0[r] * inv + lf_pe[base + c16];
        float v1f = o1[r] * inv + lf_pe[base + 16 + c16];
        outb[base + c16]      = __float2bfloat16(v0f);
        outb[base + 16 + c16] = __float2bfloat16(v1f);
    }
}

// ---------------------------------------------------------------------------
extern "C" void kernel_launch(void* const* d_in, const int* in_sizes, int n_in,
                              void* d_out, int out_size, void* d_ws, size_t ws_size,
                              hipStream_t stream) {
    const float* lf    = (const float*)d_in[0];
    const float* gfeat = (const float*)d_in[1];
    const float* Wq    = (const float*)d_in[2];
    const float* bq    = (const float*)d_in[3];
    const float* Wk    = (const float*)d_in[4];
    const float* bk    = (const float*)d_in[5];
    const float* Wv    = (const float*)d_in[6];
    const float* bv    = (const float*)d_in[7];
    const float* Wo    = (const float*)d_in[8];
    const float* bo    = (const float*)d_in[9];

    char* ws = (char*)d_ws;
    float*          lf_pe_f32 = (float*)(ws);                               // 4 MB
    __hip_bfloat16* lf_pe_b   = (__hip_bfloat16*)(ws + (4u  << 20));        // 2 MB
    __hip_bfloat16* gf_pe_b   = (__hip_bfloat16*)(ws + (6u  << 20));        // 8 MB
    __hip_bfloat16* W4        = (__hip_bfloat16*)(ws + (14u << 20));        // 0.5 MB
    __hip_bfloat16* Qb        = (__hip_bfloat16*)(ws + (15u << 20));        // 2 MB
    __hip_bfloat16* Kb        = (__hip_bfloat16*)(ws + (17u << 20));        // 8 MB
    __hip_bfloat16* Vtb       = (__hip_bfloat16*)(ws + (25u << 20));        // 8 MB
    __hip_bfloat16* ALb       = (__hip_bfloat16*)(ws + (33u << 20));        // 2 MB

    prep_local<<<dim3(NB * NPTS * DD / 256), dim3(256), 0, stream>>>(lf, lf_pe_f32, lf_pe_b);
    prep_global<<<dim3(HWW / 32, DD / 32, NB), dim3(32, 32), 0, stream>>>(gfeat, gf_pe_b);
    w2b<<<dim3(4 * DD * DD / 256), dim3(256), 0, stream>>>(Wq, Wk, Wv, Wo, W4);

    gemm256<0><<<dim3(NB * NPTS / 64, 4), dim3(256), 0, stream>>>(lf_pe_b, W4,               bq, (void*)Qb);
    gemm256<1><<<dim3(NB * HWW  / 64, 4), dim3(256), 0, stream>>>(gf_pe_b, W4 + 1 * DD * DD, bk, (void*)Kb);
    gemm256<2><<<dim3(NB * HWW  / 64, 4), dim3(256), 0, stream>>>(gf_pe_b, W4 + 2 * DD * DD, bv, (void*)Vtb);

    attn<<<dim3(NPTS / 64, NB * NHEAD), dim3(256), 0, stream>>>(Qb, Kb, Vtb, lf_pe_f32, ALb);

    gemm256<3><<<dim3(NB * NPTS / 64, 4), dim3(256), 0, stream>>>(ALb, W4 + 3 * DD * DD, bo, d_out);
}

// Round 2
// 205.009 us; speedup vs baseline: 1.4004x; 1.4004x over previous
//
#include <hip/hip_runtime.h>
#include <hip/hip_bf16.h>
#include <math.h>

// Problem constants
#define NB    4
#define NPTS  1024
#define DD    256
#define HH    64
#define WW    64
#define HWW   4096
#define NHEAD 8
#define DHD   32

typedef short s8v  __attribute__((ext_vector_type(8)));   // 8 x bf16 bits
typedef float f4v  __attribute__((ext_vector_type(4)));

#define MFMA_BF16 __builtin_amdgcn_mfma_f32_16x16x32_bf16

// -log(10000)/256
#define PE_FACT (-9.210340371976184f / 256.0f)
// log2(e)/sqrt(32) -- folded into Q so S-MFMA output is the exp2 argument
#define QSCALE 0.2550348637f

// ---------------------------------------------------------------------------
// K1: lf_pe = local_feat + pos_enc(32x32 grid); store fp32 (residual) + bf16
// ---------------------------------------------------------------------------
__global__ __launch_bounds__(256) void prep_local(const float* __restrict__ lf,
                                                  float* __restrict__ lf_pe_f32,
                                                  __hip_bfloat16* __restrict__ lf_pe_b) {
    int idx = blockIdx.x * 256 + threadIdx.x;      // < 4*1024*256
    int c = idx & 255;
    int p = (idx >> 8) & 1023;
    float div = __expf((float)(c & ~1) * PE_FACT);
    float pe;
    if (c & 1) {
        float y = (float)(p >> 5) * (1.0f / 31.0f);
        pe = __cosf(y * div);
    } else {
        float x = (float)(p & 31) * (1.0f / 31.0f);
        pe = __sinf(x * div);
    }
    float v = lf[idx] + pe;
    lf_pe_f32[idx] = v;
    lf_pe_b[idx] = __float2bfloat16(v);
}

// ---------------------------------------------------------------------------
// K2: gf_pe[n,p,c] = global_feat[n,c,p] + pos_enc(64x64 grid)  (LDS transpose)
// ---------------------------------------------------------------------------
__global__ __launch_bounds__(1024) void prep_global(const float* __restrict__ gfeat,
                                                    __hip_bfloat16* __restrict__ gf_pe_b) {
    __shared__ float tile[32][33];
    int n  = blockIdx.z;
    int p0 = blockIdx.x * 32;
    int c0 = blockIdx.y * 32;
    int tx = threadIdx.x, ty = threadIdx.y;
    tile[ty][tx] = gfeat[((size_t)n * DD + (c0 + ty)) * HWW + p0 + tx];
    __syncthreads();
    int p = p0 + ty, c = c0 + tx;
    float div = __expf((float)(c & ~1) * PE_FACT);
    float pe;
    if (c & 1) {
        float y = (float)(p >> 6) * (1.0f / 63.0f);
        pe = __cosf(y * div);
    } else {
        float x = (float)(p & 63) * (1.0f / 63.0f);
        pe = __sinf(x * div);
    }
    gf_pe_b[((size_t)n * HWW + p) * DD + c] = __float2bfloat16(tile[tx][ty] + pe);
}

// ---------------------------------------------------------------------------
// K3: weights -> bf16 (Wq | Wk | Wv | Wo packed consecutively)
// ---------------------------------------------------------------------------
__global__ __launch_bounds__(256) void w2b(const float* __restrict__ wq, const float* __restrict__ wk,
                                           const float* __restrict__ wv, const float* __restrict__ wo,
                                           __hip_bfloat16* __restrict__ out) {
    int idx = blockIdx.x * 256 + threadIdx.x;      // < 4*65536
    int m = idx >> 16, r = idx & 65535;
    const float* src = (m == 0) ? wq : (m == 1) ? wk : (m == 2) ? wv : wo;
    out[idx] = __float2bfloat16(src[r]);
}

// ---------------------------------------------------------------------------
// K4: GEMM  out = A(M,256) @ W^T(256,256) + bias
//   MODE 0: Q  -> bf16 (n,h,NP,32), pre-scaled by QSCALE (exp2-ready scores)
//   MODE 3: fp32 (M,256) to d_out
// ---------------------------------------------------------------------------
template <int MODE>
__global__ __launch_bounds__(256) void gemm256(const __hip_bfloat16* __restrict__ A,
                                               const __hip_bfloat16* __restrict__ Wb,
                                               const float* __restrict__ bias,
                                               void* __restrict__ outp) {
    int wave = threadIdx.x >> 6;
    int lane = threadIdx.x & 63;
    int quad = lane >> 4, c16 = lane & 15;
    int m0 = blockIdx.x * 64 + wave * 16;
    int c0 = blockIdx.y * 64;
    const short* Ab = (const short*)A;
    const short* Wp = (const short*)Wb;

    f4v acc0 = {0.f, 0.f, 0.f, 0.f}, acc1 = acc0, acc2 = acc0, acc3 = acc0;
    int arow = (m0 + c16) * DD + quad * 8;
#pragma unroll
    for (int ks = 0; ks < 8; ++ks) {
        s8v a  = *(const s8v*)(Ab + arow + ks * 32);
        s8v b0 = *(const s8v*)(Wp + (c0 +  0 + c16) * DD + ks * 32 + quad * 8);
        s8v b1 = *(const s8v*)(Wp + (c0 + 16 + c16) * DD + ks * 32 + quad * 8);
        s8v b2 = *(const s8v*)(Wp + (c0 + 32 + c16) * DD + ks * 32 + quad * 8);
        s8v b3 = *(const s8v*)(Wp + (c0 + 48 + c16) * DD + ks * 32 + quad * 8);
        acc0 = MFMA_BF16(a, b0, acc0, 0, 0, 0);
        acc1 = MFMA_BF16(a, b1, acc1, 0, 0, 0);
        acc2 = MFMA_BF16(a, b2, acc2, 0, 0, 0);
        acc3 = MFMA_BF16(a, b3, acc3, 0, 0, 0);
    }
#pragma unroll
    for (int t = 0; t < 4; ++t) {
        f4v acc = (t == 0) ? acc0 : (t == 1) ? acc1 : (t == 2) ? acc2 : acc3;
        int col = c0 + t * 16 + c16;
        float bv = bias[col];
#pragma unroll
        for (int r = 0; r < 4; ++r) {
            int row = m0 + quad * 4 + r;
            float v = acc[r] + bv;
            if (MODE == 0) {            // Q: (n,h,NP,32), pre-scaled
                int n = row >> 10, p = row & 1023, h = col >> 5, dh = col & 31;
                ((__hip_bfloat16*)outp)[(((size_t)(n * NHEAD + h) << 10) + p) * DHD + dh] =
                    __float2bfloat16(v * QSCALE);
            } else {                    // fp32 out
                ((float*)outp)[(size_t)row * DD + col] = v;
            }
        }
    }
}

// ---------------------------------------------------------------------------
// K4b: fused K+V GEMM: reads A once, writes both K and V in (n,h,HW,32) bf16
// ---------------------------------------------------------------------------
__global__ __launch_bounds__(256) void gemmKV(const __hip_bfloat16* __restrict__ A,
                                              const __hip_bfloat16* __restrict__ Wk,
                                              const __hip_bfloat16* __restrict__ Wv,
                                              const float* __restrict__ bk,
                                              const float* __restrict__ bv,
                                              __hip_bfloat16* __restrict__ Kb,
                                              __hip_bfloat16* __restrict__ Vb) {
    int wave = threadIdx.x >> 6;
    int lane = threadIdx.x & 63;
    int quad = lane >> 4, c16 = lane & 15;
    int m0 = blockIdx.x * 64 + wave * 16;
    int c0 = blockIdx.y * 64;
    const short* Ab  = (const short*)A;
    const short* Wkp = (const short*)Wk;
    const short* Wvp = (const short*)Wv;

    f4v ak0 = {0.f,0.f,0.f,0.f}, ak1 = ak0, ak2 = ak0, ak3 = ak0;
    f4v av0 = ak0, av1 = ak0, av2 = ak0, av3 = ak0;
    int arow = (m0 + c16) * DD + quad * 8;
#pragma unroll
    for (int ks = 0; ks < 8; ++ks) {
        s8v a = *(const s8v*)(Ab + arow + ks * 32);
        int wrow = ks * 32 + quad * 8;
        s8v k0 = *(const s8v*)(Wkp + (c0 +  0 + c16) * DD + wrow);
        s8v k1 = *(const s8v*)(Wkp + (c0 + 16 + c16) * DD + wrow);
        s8v k2 = *(const s8v*)(Wkp + (c0 + 32 + c16) * DD + wrow);
        s8v k3 = *(const s8v*)(Wkp + (c0 + 48 + c16) * DD + wrow);
        ak0 = MFMA_BF16(a, k0, ak0, 0, 0, 0);
        ak1 = MFMA_BF16(a, k1, ak1, 0, 0, 0);
        ak2 = MFMA_BF16(a, k2, ak2, 0, 0, 0);
        ak3 = MFMA_BF16(a, k3, ak3, 0, 0, 0);
        s8v v0 = *(const s8v*)(Wvp + (c0 +  0 + c16) * DD + wrow);
        s8v v1 = *(const s8v*)(Wvp + (c0 + 16 + c16) * DD + wrow);
        s8v v2 = *(const s8v*)(Wvp + (c0 + 32 + c16) * DD + wrow);
        s8v v3 = *(const s8v*)(Wvp + (c0 + 48 + c16) * DD + wrow);
        av0 = MFMA_BF16(a, v0, av0, 0, 0, 0);
        av1 = MFMA_BF16(a, v1, av1, 0, 0, 0);
        av2 = MFMA_BF16(a, v2, av2, 0, 0, 0);
        av3 = MFMA_BF16(a, v3, av3, 0, 0, 0);
    }
#pragma unroll
    for (int t = 0; t < 4; ++t) {
        f4v accK = (t == 0) ? ak0 : (t == 1) ? ak1 : (t == 2) ? ak2 : ak3;
        f4v accV = (t == 0) ? av0 : (t == 1) ? av1 : (t == 2) ? av2 : av3;
        int col = c0 + t * 16 + c16;
        float bkv = bk[col], bvv = bv[col];
        int h = col >> 5, dh = col & 31;
#pragma unroll
        for (int r = 0; r < 4; ++r) {
            int row = m0 + quad * 4 + r;
            int n = row >> 12, p = row & 4095;
            size_t o = (((size_t)(n * NHEAD + h) << 12) + p) * DHD + dh;
            Kb[o] = __float2bfloat16(accK[r] + bkv);
            Vb[o] = __float2bfloat16(accV[r] + bvv);
        }
    }
}

// ---------------------------------------------------------------------------
// K5: attention, no-max unnormalized exp2 softmax, KB=128 keys/iter.
//   grid (NP/64, N*HEADS), block 256 (4 waves, each 16 q-rows).
//   K/V tiles cooperatively staged in LDS (register double-buffered);
//   V transposed into dword-packed vt[dh][keypair] during staging.
//   out = (P V) / rowsum(P) + lf_pe  -> bf16 (n, p, 256)
// ---------------------------------------------------------------------------
__global__ __launch_bounds__(256) void attn(const __hip_bfloat16* __restrict__ Q,
                                            const __hip_bfloat16* __restrict__ Kg,
                                            const __hip_bfloat16* __restrict__ Vg,
                                            const float* __restrict__ lf_pe,
                                            __hip_bfloat16* __restrict__ outb) {
    // K tile: [128 keys][40 shorts] (32 data + 8 pad) -> conflict-free b128 rows
    __shared__ __align__(16) short kt[128 * 40];                  // 10240 B
    // V tile transposed: [32 dh][68 dw] (64 keypairs + 4 pad)
    __shared__ __align__(16) unsigned int vt[32 * 68];            //  8704 B
    // P tile per wave: [16 q][136 shorts] (128 + 8 pad)
    __shared__ __align__(16) __hip_bfloat16 plds[4][16][136];     // 17408 B

    int tid = threadIdx.x;
    int wave = tid >> 6, lane = tid & 63;
    int quad = lane >> 4, c16 = lane & 15;
    int bh = blockIdx.y;                 // n*8 + h
    int m0 = blockIdx.x * 64 + wave * 16;

    const short* Qs = (const short*)Q + (size_t)bh * NPTS * DHD;
    const short* Ks = (const short*)Kg + (size_t)bh * HWW * DHD;
    const short* Vs = (const short*)Vg + (size_t)bh * HWW * DHD;

    // staging assignments
    int skey = tid >> 1, shalf = (tid & 1) * 16;   // K: thread covers 16 shorts of one key row
    int kp = tid & 63, dhg = tid >> 6;             // V: keypair + 8-dh group

    s8v aq = *(const s8v*)(Qs + (m0 + c16) * DHD + quad * 8);

    // prologue: load tile 0 into registers
    s8v kr0 = *(const s8v*)(Ks + (size_t)skey * DHD + shalf);
    s8v kr1 = *(const s8v*)(Ks + (size_t)skey * DHD + shalf + 8);
    s8v var = *(const s8v*)(Vs + (size_t)(2 * kp)     * DHD + dhg * 8);
    s8v vbr = *(const s8v*)(Vs + (size_t)(2 * kp + 1) * DHD + dhg * 8);

    f4v o0 = {0.f, 0.f, 0.f, 0.f}, o1 = {0.f, 0.f, 0.f, 0.f};
    const f4v zf = {0.f, 0.f, 0.f, 0.f};
    float lrow[4] = {0.f, 0.f, 0.f, 0.f};

    for (int j0 = 0; j0 < HWW; j0 += 128) {
        __syncthreads();                       // prior iter's compute done
        *(s8v*)&kt[skey * 40 + shalf]     = kr0;
        *(s8v*)&kt[skey * 40 + shalf + 8] = kr1;
#pragma unroll
        for (int i = 0; i < 8; ++i) {
            unsigned int lo = (unsigned short)var[i];
            unsigned int hi = (unsigned short)vbr[i];
            vt[(dhg * 8 + i) * 68 + kp] = lo | (hi << 16);
        }
        __syncthreads();                       // tiles visible
        int jn = j0 + 128;
        if (jn < HWW) {                        // prefetch next tile (overlaps compute)
            kr0 = *(const s8v*)(Ks + (size_t)(jn + skey) * DHD + shalf);
            kr1 = *(const s8v*)(Ks + (size_t)(jn + skey) * DHD + shalf + 8);
            var = *(const s8v*)(Vs + (size_t)(jn + 2 * kp)     * DHD + dhg * 8);
            vbr = *(const s8v*)(Vs + (size_t)(jn + 2 * kp + 1) * DHD + dhg * 8);
        }

        // scores (exp2 argument directly: Q pre-scaled by log2e/sqrt(32))
        f4v s[8];
#pragma unroll
        for (int t = 0; t < 8; ++t) {
            s8v kb = *(const s8v*)&kt[(t * 16 + c16) * 40 + quad * 8];
            s[t] = MFMA_BF16(aq, kb, zf, 0, 0, 0);
        }
        // unnormalized softmax: p = exp2(s); rowsum deferred to epilogue
#pragma unroll
        for (int r = 0; r < 4; ++r) {
            float ps = 0.f;
#pragma unroll
            for (int t = 0; t < 8; ++t) {
                float p = exp2f(s[t][r]);
                ps += p;
                plds[wave][quad * 4 + r][t * 16 + c16] = __float2bfloat16(p);
            }
            lrow[r] += ps;
        }
        // P @ V
#pragma unroll
        for (int tp = 0; tp < 4; ++tp) {
            s8v pa = *(const s8v*)&plds[wave][c16][tp * 32 + quad * 8];
            s8v v0 = *(const s8v*)&vt[c16        * 68 + tp * 16 + quad * 4];
            s8v v1 = *(const s8v*)&vt[(16 + c16) * 68 + tp * 16 + quad * 4];
            o0 = MFMA_BF16(pa, v0, o0, 0, 0, 0);
            o1 = MFMA_BF16(pa, v1, o1, 0, 0, 0);
        }
    }

    int b = bh >> 3, h = bh & 7;
#pragma unroll
    for (int r = 0; r < 4; ++r) {
        float lr = lrow[r];
        lr += __shfl_xor(lr, 1, 16);
        lr += __shfl_xor(lr, 2, 16);
        lr += __shfl_xor(lr, 4, 16);
        lr += __shfl_xor(lr, 8, 16);
        float inv = 1.0f / lr;
        int q = m0 + quad * 4 + r;
        size_t base = (((size_t)b << 10) + q) * DD + (h << 5);
        outb[base + c16]      = __float2bfloat16(o0[r] * inv + lf_pe[base + c16]);
        outb[base + 16 + c16] = __float2bfloat16(o1[r] * inv + lf_pe[base + 16 + c16]);
    }
}

// ---------------------------------------------------------------------------
extern "C" void kernel_launch(void* const* d_in, const int* in_sizes, int n_in,
                              void* d_out, int out_size, void* d_ws, size_t ws_size,
                              hipStream_t stream) {
    const float* lf    = (const float*)d_in[0];
    const float* gfeat = (const float*)d_in[1];
    const float* Wq    = (const float*)d_in[2];
    const float* bq    = (const float*)d_in[3];
    const float* Wk    = (const float*)d_in[4];
    const float* bk    = (const float*)d_in[5];
    const float* Wv    = (const float*)d_in[6];
    const float* bv    = (const float*)d_in[7];
    const float* Wo    = (const float*)d_in[8];
    const float* bo    = (const float*)d_in[9];

    char* ws = (char*)d_ws;
    float*          lf_pe_f32 = (float*)(ws);                               // 4 MB
    __hip_bfloat16* lf_pe_b   = (__hip_bfloat16*)(ws + (4u  << 20));        // 2 MB
    __hip_bfloat16* gf_pe_b   = (__hip_bfloat16*)(ws + (6u  << 20));        // 8 MB
    __hip_bfloat16* W4        = (__hip_bfloat16*)(ws + (14u << 20));        // 0.5 MB
    __hip_bfloat16* Qb        = (__hip_bfloat16*)(ws + (15u << 20));        // 2 MB
    __hip_bfloat16* Kb        = (__hip_bfloat16*)(ws + (17u << 20));        // 8 MB
    __hip_bfloat16* Vb        = (__hip_bfloat16*)(ws + (25u << 20));        // 8 MB
    __hip_bfloat16* ALb       = (__hip_bfloat16*)(ws + (33u << 20));        // 2 MB

    prep_local<<<dim3(NB * NPTS * DD / 256), dim3(256), 0, stream>>>(lf, lf_pe_f32, lf_pe_b);
    prep_global<<<dim3(HWW / 32, DD / 32, NB), dim3(32, 32), 0, stream>>>(gfeat, gf_pe_b);
    w2b<<<dim3(4 * DD * DD / 256), dim3(256), 0, stream>>>(Wq, Wk, Wv, Wo, W4);

    gemm256<0><<<dim3(NB * NPTS / 64, 4), dim3(256), 0, stream>>>(lf_pe_b, W4, bq, (void*)Qb);
    gemmKV<<<dim3(NB * HWW / 64, 4), dim3(256), 0, stream>>>(gf_pe_b, W4 + 1 * DD * DD,
                                                             W4 + 2 * DD * DD, bk, bv, Kb, Vb);

    attn<<<dim3(NPTS / 64, NB * NHEAD), dim3(256), 0, stream>>>(Qb, Kb, Vb, lf_pe_f32, ALb);

    gemm256<3><<<dim3(NB * NPTS / 64, 4), dim3(256), 0, stream>>>(ALb, W4 + 3 * DD * DD, bo, d_out);
}